// Round 13
// baseline (261.787 us; speedup 1.0000x reference)
//
#include <hip/hip_runtime.h>
#include <hip/hip_fp16.h>

// ---------------------------------------------------------------------------
// 3-layer GCN, CSR-gather, fp16 dataflow + MFMA GEMM, fused pipeline:
//   gemm1:        HWS1 = half(dis * (x @ W1))            (MFMA 16x16x32 f16)
//   gather+gemm2: h1 = relu(dis*Σ HWS1 + b1) -> LDS -> HWS2 = half(dis*(h1@W2))
//                 [512 thr; dynamic LDS node queue; Wt prefetched pre-barrier]
//   gather+gemv:  hw3s = dis * dot(relu(dis*Σ HWS2 + b2), W3)
//   gather3:      out = relu(dis*Σ hw3s + b3)
// Lessons: R4/R5 never force __launch_bounds__ min-waves (VGPR cap 256/w ->
// spills). R7/R8: gather is bytes-below-L2 bound (fp16 halves it). R11/R12:
// fused gather loses TLP -> 512-thr blocks; static 4-node/half-wave split
// leaves ~35% barrier-straggler waste -> dynamic queue.
// ---------------------------------------------------------------------------

typedef _Float16 v8h __attribute__((ext_vector_type(8)));
typedef float v4f __attribute__((ext_vector_type(4)));

// fused: edge count (blocks [0,BE)) + weight cast/transpose (blocks [BE,BE+64))
__global__ __launch_bounds__(256) void k_count_wcast(const int* __restrict__ dst,
                                                     int* __restrict__ cnt, int nE,
                                                     int BE,
                                                     const float* __restrict__ W1,
                                                     const float* __restrict__ W2,
                                                     __half* __restrict__ Wt1,
                                                     __half* __restrict__ Wt2) {
    int b = blockIdx.x;
    if (b < BE) {
        int e = b * 256 + threadIdx.x;
        if (e < nE) atomicAdd(&cnt[dst[e]], 1);
    } else {
        int i = (b - BE) * 256 + threadIdx.x;   // 0..16383
        int k = i >> 7, c = i & 127;
        Wt1[c * 128 + k] = __float2half(W1[i]);
        Wt2[c * 128 + k] = __float2half(W2[i]);
    }
}

// scan stage 1 + fused dis = rsqrt(cnt+1)
__global__ __launch_bounds__(256) void k_scan_blk(const int* __restrict__ cnt,
                                                  float* __restrict__ dis,
                                                  int* __restrict__ excl,
                                                  int* __restrict__ blk_sum, int nN) {
    __shared__ int sm[256];
    const int t = threadIdx.x;
    int i = blockIdx.x * 256 + t;
    int v = (i < nN) ? cnt[i] : 0;
    if (i < nN) dis[i] = rsqrtf((float)v + 1.0f);
    sm[t] = v;
    __syncthreads();
#pragma unroll
    for (int off = 1; off < 256; off <<= 1) {
        int x = (t >= off) ? sm[t - off] : 0;
        __syncthreads();
        sm[t] += x;
        __syncthreads();
    }
    if (i < nN) excl[i] = sm[t] - v;
    if (t == 255) blk_sum[blockIdx.x] = sm[255];
}

// stage 2+3 fused: every block scans blk_sum (nB<=256) in LDS, then adds.
__global__ __launch_bounds__(256) void k_scan_add(const int* __restrict__ excl,
                                                  const int* __restrict__ blk_sum,
                                                  int* __restrict__ row_ptr,
                                                  int* __restrict__ cursor,
                                                  int nN, int nB) {
    __shared__ int sm[256];
    const int t = threadIdx.x;
    int v = (t < nB) ? blk_sum[t] : 0;
    sm[t] = v;
    __syncthreads();
#pragma unroll
    for (int off = 1; off < 256; off <<= 1) {
        int x = (t >= off) ? sm[t - off] : 0;
        __syncthreads();
        sm[t] += x;
        __syncthreads();
    }
    // sm[j] = inclusive sum; exclusive offset for block j is sm[j]-blk_sum[j]
    int i = blockIdx.x * 256 + t;
    if (i < nN) {
        int b = i >> 8;
        int off = sm[b] - blk_sum[b];
        int val = excl[i] + off;
        row_ptr[i] = val;
        cursor[i] = val;
    }
    if (i == 0) row_ptr[nN] = sm[255];
}

__global__ __launch_bounds__(256) void k_bin(const int* __restrict__ src,
                                             const int* __restrict__ dst,
                                             int* __restrict__ cursor,
                                             int* __restrict__ src_csr, int nE) {
    int e = blockIdx.x * 256 + threadIdx.x;
    if (e >= nE) return;
    int s = src[e], d = dst[e];
    int pos = atomicAdd(&cursor[d], 1);
    src_csr[pos] = s;
}

// register-accumulated pull of one node row (32 lanes x 4 halves = 128 cols),
// fp32 acc; includes the self term HWS[g].
__device__ __forceinline__ float4 gather_row(const float2* __restrict__ Hv,
                                             const int* __restrict__ row_ptr,
                                             const int* __restrict__ src_csr,
                                             int g, int f4) {
    int beg = row_ptr[g], end = row_ptr[g + 1];
    float2 r0 = Hv[(size_t)g * 32 + f4];
    float2 lo = __half22float2(*(__half2*)&r0.x);
    float2 hi = __half22float2(*(__half2*)&r0.y);
    float4 acc = make_float4(lo.x, lo.y, hi.x, hi.y);
    int e = beg;
    for (; e + 8 <= end; e += 8) {
        int s[8];
#pragma unroll
        for (int j = 0; j < 8; ++j) s[j] = src_csr[e + j];
        float2 r[8];
#pragma unroll
        for (int j = 0; j < 8; ++j) r[j] = Hv[(size_t)s[j] * 32 + f4];
#pragma unroll
        for (int j = 0; j < 8; ++j) {
            float2 l2 = __half22float2(*(__half2*)&r[j].x);
            float2 h2 = __half22float2(*(__half2*)&r[j].y);
            acc.x += l2.x; acc.y += l2.y; acc.z += h2.x; acc.w += h2.y;
        }
    }
    if (e + 4 <= end) {
        int s[4];
#pragma unroll
        for (int j = 0; j < 4; ++j) s[j] = src_csr[e + j];
        float2 r[4];
#pragma unroll
        for (int j = 0; j < 4; ++j) r[j] = Hv[(size_t)s[j] * 32 + f4];
#pragma unroll
        for (int j = 0; j < 4; ++j) {
            float2 l2 = __half22float2(*(__half2*)&r[j].x);
            float2 h2 = __half22float2(*(__half2*)&r[j].y);
            acc.x += l2.x; acc.y += l2.y; acc.z += h2.x; acc.w += h2.y;
        }
        e += 4;
    }
    for (; e < end; ++e) {
        float2 r = Hv[(size_t)src_csr[e] * 32 + f4];
        float2 l2 = __half22float2(*(__half2*)&r.x);
        float2 h2 = __half22float2(*(__half2*)&r.y);
        acc.x += l2.x; acc.y += l2.y; acc.z += h2.x; acc.w += h2.y;
    }
    return acc;
}

// layer-1 MFMA GEMM: HWS1 = half( dis[row] * (x @ W1) ), x fp32 [nN x 128].
__global__ __launch_bounds__(256) void k_gemm_mfma(const float* __restrict__ X32,
                                                   const __half* __restrict__ Wt,
                                                   const float* __restrict__ dis,
                                                   __half* __restrict__ HWS,
                                                   int nrows) {
    __shared__ __half xs[64 * 136];
    const int t = threadIdx.x;
    const int row0 = blockIdx.x * 64;

#pragma unroll
    for (int i = 0; i < 8; ++i) {
        int f = t + i * 256;
        int r = f >> 5, k4 = f & 31;
        int gr = row0 + r;
        float4 v = make_float4(0.f, 0.f, 0.f, 0.f);
        if (gr < nrows) v = ((const float4*)X32)[(size_t)gr * 32 + k4];
        __half2 h01 = __float22half2_rn(make_float2(v.x, v.y));
        __half2 h23 = __float22half2_rn(make_float2(v.z, v.w));
        float2 packed;
        *(__half2*)&packed.x = h01;
        *(__half2*)&packed.y = h23;
        *(float2*)&xs[r * 136 + k4 * 4] = packed;
    }
    __syncthreads();

    const int w = t >> 6;
    const int l = t & 63;
    const int mrow = l & 15;
    const int kq = l >> 4;

    v8h a[4];
#pragma unroll
    for (int kk = 0; kk < 4; ++kk)
        a[kk] = *(const v8h*)&xs[(w * 16 + mrow) * 136 + kk * 32 + kq * 8];

    v4f acc[8];
#pragma unroll
    for (int c = 0; c < 8; ++c) acc[c] = (v4f){0.f, 0.f, 0.f, 0.f};

#pragma unroll
    for (int kk = 0; kk < 4; ++kk) {
#pragma unroll
        for (int c = 0; c < 8; ++c) {
            v8h b = *(const v8h*)&Wt[(size_t)(c * 16 + mrow) * 128 + kk * 32 + kq * 8];
            acc[c] = __builtin_amdgcn_mfma_f32_16x16x32_f16(a[kk], b, acc[c], 0, 0, 0);
        }
    }

    float dn[4];
#pragma unroll
    for (int r = 0; r < 4; ++r) {
        int grow = row0 + w * 16 + kq * 4 + r;
        dn[r] = (grow < nrows) ? dis[grow] : 0.f;
    }
#pragma unroll
    for (int c = 0; c < 8; ++c) {
#pragma unroll
        for (int r = 0; r < 4; ++r) {
            int grow = row0 + w * 16 + kq * 4 + r;
            if (grow < nrows)
                HWS[(size_t)grow * 128 + c * 16 + mrow] =
                    __float2half(acc[c][r] * dn[r]);
        }
    }
}

// FUSED layer-1 gather + layer-2 GEMM, 512 threads.
//   phase 1: 16 half-waves pull nodes from an LDS queue (load-balance),
//            h1 = relu(dis*Σ HWS1 + b1) -> LDS fp16
//   phase 2: 8 MFMA waves; wave w: rows (w&3)*16..+16, col-tiles (w>>2)*4..+4
//   Wt fragments prefetched BEFORE the gather loop (latency hidden behind it).
__global__ __launch_bounds__(512) void k_gather_gemm(const __half* __restrict__ HWS1,
                                                     const int* __restrict__ row_ptr,
                                                     const int* __restrict__ src_csr,
                                                     const float* __restrict__ dis,
                                                     const float* __restrict__ bias,
                                                     const __half* __restrict__ Wt,
                                                     __half* __restrict__ HWS2,
                                                     int nN) {
    __shared__ __half xs[64 * 136];
    __shared__ int q;
    const int t = threadIdx.x;
    const int row0 = blockIdx.x * 64;
    const int f4 = t & 31;
    const float2* Hv = (const float2*)HWS1;
    const float4 bv = ((const float4*)bias)[f4];

    const int w = t >> 6;        // wave 0..7
    const int l = t & 63;
    const int mrow = l & 15;
    const int kq = l >> 4;
    const int rgrp = (w & 3) * 16;
    const int cgrp = (w >> 2) * 4;

    if (t == 0) q = 0;

    // prefetch all 16 B-fragments (independent of gather) — 64 VGPRs
    v8h bfrag[4][4];
#pragma unroll
    for (int kk = 0; kk < 4; ++kk)
#pragma unroll
        for (int c = 0; c < 4; ++c)
            bfrag[kk][c] = *(const v8h*)&Wt[(size_t)((cgrp + c) * 16 + mrow) * 128
                                            + kk * 32 + kq * 8];
    __syncthreads();   // q visible

    // dynamic gather: half-waves grab node slots until the block's 64 are done
    const int bcast_lane = (l >> 5) << 5;   // lane 0 or 32 of this wave
    for (;;) {
        int lr = 0;
        if (f4 == 0) lr = atomicAdd(&q, 1);
        lr = __shfl(lr, bcast_lane, 64);
        if (lr >= 64) break;
        int g = row0 + lr;
        float4 h = make_float4(0.f, 0.f, 0.f, 0.f);
        if (g < nN) {
            float4 acc = gather_row(Hv, row_ptr, src_csr, g, f4);
            float dn = dis[g];
            h.x = fmaxf(acc.x * dn + bv.x, 0.f);
            h.y = fmaxf(acc.y * dn + bv.y, 0.f);
            h.z = fmaxf(acc.z * dn + bv.z, 0.f);
            h.w = fmaxf(acc.w * dn + bv.w, 0.f);
        }
        __half2 h01 = __float22half2_rn(make_float2(h.x, h.y));
        __half2 h23 = __float22half2_rn(make_float2(h.z, h.w));
        float2 packed;
        *(__half2*)&packed.x = h01;
        *(__half2*)&packed.y = h23;
        *(float2*)&xs[lr * 136 + f4 * 4] = packed;
    }
    __syncthreads();

    v8h a[4];
#pragma unroll
    for (int kk = 0; kk < 4; ++kk)
        a[kk] = *(const v8h*)&xs[(rgrp + mrow) * 136 + kk * 32 + kq * 8];

    v4f acc[4];
#pragma unroll
    for (int c = 0; c < 4; ++c) acc[c] = (v4f){0.f, 0.f, 0.f, 0.f};

#pragma unroll
    for (int kk = 0; kk < 4; ++kk)
#pragma unroll
        for (int c = 0; c < 4; ++c)
            acc[c] = __builtin_amdgcn_mfma_f32_16x16x32_f16(a[kk], bfrag[kk][c],
                                                            acc[c], 0, 0, 0);

    float dn4[4];
#pragma unroll
    for (int r = 0; r < 4; ++r) {
        int grow = row0 + rgrp + kq * 4 + r;
        dn4[r] = (grow < nN) ? dis[grow] : 0.f;
    }
#pragma unroll
    for (int c = 0; c < 4; ++c) {
#pragma unroll
        for (int r = 0; r < 4; ++r) {
            int grow = row0 + rgrp + kq * 4 + r;
            if (grow < nN)
                HWS2[(size_t)grow * 128 + (cgrp + c) * 16 + mrow] =
                    __float2half(acc[c][r] * dn4[r]);
        }
    }
}

// FUSED layer-2 gather + layer-3 gemv:
//   hw3s[g] = dis[g] * dot(relu(dis[g]*Σ HWS2 + b2), W3)
__global__ __launch_bounds__(256) void k_gather_gemv(const __half* __restrict__ HWS2,
                                                     const int* __restrict__ row_ptr,
                                                     const int* __restrict__ src_csr,
                                                     const float* __restrict__ dis,
                                                     const float* __restrict__ bias,
                                                     const float* __restrict__ W3,
                                                     float* __restrict__ hw3s, int nN) {
    int g = blockIdx.x * 8 + (threadIdx.x >> 5);
    if (g >= nN) return;
    int f4 = threadIdx.x & 31;
    float4 acc = gather_row((const float2*)HWS2, row_ptr, src_csr, g, f4);
    float dn = dis[g];
    float4 bv = ((const float4*)bias)[f4];
    float4 w  = ((const float4*)W3)[f4];
    float sum = fmaxf(acc.x * dn + bv.x, 0.f) * w.x
              + fmaxf(acc.y * dn + bv.y, 0.f) * w.y
              + fmaxf(acc.z * dn + bv.z, 0.f) * w.z
              + fmaxf(acc.w * dn + bv.w, 0.f) * w.w;
#pragma unroll
    for (int off = 16; off > 0; off >>= 1) sum += __shfl_down(sum, off, 32);
    if (f4 == 0) hw3s[g] = sum * dn;
}

// scalar pull-aggregation + final relu -> d_out
__global__ __launch_bounds__(256) void k_gather3(const float* __restrict__ hw3s,
                                                 const int* __restrict__ row_ptr,
                                                 const int* __restrict__ src_csr,
                                                 const float* __restrict__ dis,
                                                 const float* __restrict__ b3,
                                                 float* __restrict__ out, int nN) {
    int i = blockIdx.x * 256 + threadIdx.x;
    if (i >= nN) return;
    float acc = hw3s[i];
    int beg = row_ptr[i], end = row_ptr[i + 1];
    for (int e = beg; e < end; ++e) acc += hw3s[src_csr[e]];
    out[i] = fmaxf(acc * dis[i] + b3[0], 0.f);
}

extern "C" void kernel_launch(void* const* d_in, const int* in_sizes, int n_in,
                              void* d_out, int out_size, void* d_ws, size_t ws_size,
                              hipStream_t stream) {
    const float* x  = (const float*)d_in[0];
    const int*   ei = (const int*)d_in[1];
    const float* W1 = (const float*)d_in[2];
    const float* b1 = (const float*)d_in[3];
    const float* W2 = (const float*)d_in[4];
    const float* b2 = (const float*)d_in[5];
    const float* W3 = (const float*)d_in[6];
    const float* b3 = (const float*)d_in[7];

    const int nN = in_sizes[0] / 128;
    const int nE = in_sizes[1] / 2;
    const int* src = ei;
    const int* dst = ei + nE;

    const int nB = (nN + 255) / 256;   // scan blocks (<=256)

    // workspace layout
    char* p = (char*)d_ws;
    int*    cnt      = (int*)p;           p += (size_t)nN * 4;
    int*    cursor   = (int*)p;           p += (size_t)nN * 4;
    int*    excl     = (int*)p;           p += (size_t)nN * 4;
    int*    blk_sum  = (int*)p;           p += (size_t)(nB + 1) * 4;
    int*    row_ptr  = (int*)p;           p += (size_t)(nN + 1) * 4;
    int*    src_csr  = (int*)p;           p += (size_t)nE * 4;
    float*  dis      = (float*)p;         p += (size_t)nN * 4;
    float*  hw3s     = (float*)p;         p += (size_t)nN * 4;
    p = (char*)(((uintptr_t)p + 255) & ~(uintptr_t)255);
    __half* Wt1      = (__half*)p;        p += (size_t)128 * 128 * 2;
    __half* Wt2      = (__half*)p;        p += (size_t)128 * 128 * 2;
    __half* bufA     = (__half*)p;        p += (size_t)nN * 128 * 2;  // HWS1
    p = (char*)(((uintptr_t)p + 255) & ~(uintptr_t)255);
    __half* bufB     = (__half*)p;        p += (size_t)nN * 128 * 2;  // HWS2

    const int BE  = (nE + 255) / 256;
    const int BN  = (nN + 255) / 256;
    const int BG  = (nN + 63) / 64;
    const int BGA = (nN + 7) / 8;

    // --- CSR build + norms + weight cast ---
    hipMemsetAsync(cnt, 0, (size_t)nN * sizeof(int), stream);
    k_count_wcast<<<BE + 64, 256, 0, stream>>>(dst, cnt, nE, BE, W1, W2, Wt1, Wt2);
    k_scan_blk<<<nB, 256, 0, stream>>>(cnt, dis, excl, blk_sum, nN);
    k_scan_add<<<nB, 256, 0, stream>>>(excl, blk_sum, row_ptr, cursor, nN, nB);
    k_bin     <<<BE, 256, 0, stream>>>(src, dst, cursor, src_csr, nE);

    // --- layer 1 GEMM: x -> HWS1 ---
    k_gemm_mfma<<<BG, 256, 0, stream>>>(x, Wt1, dis, bufA, nN);

    // --- fused layer-1 gather + layer-2 GEMM: HWS1 -> HWS2 (512 thr) ---
    k_gather_gemm<<<BG, 512, 0, stream>>>(bufA, row_ptr, src_csr, dis, b1, Wt2,
                                          bufB, nN);

    // --- fused layer-2 gather + layer-3 gemv: HWS2 -> hw3s ---
    k_gather_gemv<<<BGA, 256, 0, stream>>>(bufB, row_ptr, src_csr, dis, b2, W3,
                                           hw3s, nN);

    // --- layer-3 scalar gather -> d_out ---
    k_gather3<<<BN, 256, 0, stream>>>(hw3s, row_ptr, src_csr, dis, b3,
                                      (float*)d_out, nN);
}

// Round 14
// 235.133 us; speedup vs baseline: 1.1134x; 1.1134x over previous
//
#include <hip/hip_runtime.h>
#include <hip/hip_fp16.h>

// ---------------------------------------------------------------------------
// 3-layer GCN, CSR-gather, fp16 dataflow + MFMA GEMM, fused pipeline:
//   gemm1+bin:    HWS1 = half(dis * (x @ W1))  ||  CSR binning (disjoint blocks)
//   gather+gemm2: h1 = relu(dis*Σ HWS1 + b1) -> LDS -> HWS2 = half(dis*(h1@W2))
//                 [512 thr, static 4 nodes/half-wave, VGPR 32]
//   gather+gemv:  hw3s = dis * dot(relu(dis*Σ HWS2 + b2), W3)
//   gather3:      out = relu(dis*Σ hw3s + b3)
// Lessons: R4/R5 never force __launch_bounds__ min-waves (VGPR cap 256/w ->
// spills). R7/R8: gather is bytes-below-L2 bound (fp16 halves it). R11/R12:
// fused gather needs 512-thr blocks for TLP. R13: VGPR tier boundary at 64
// (m69) — Wt prefetch cost 32 extra VGPRs, halved occupancy, regressed;
// keep the hot kernel at VGPR<=32.
// ---------------------------------------------------------------------------

typedef _Float16 v8h __attribute__((ext_vector_type(8)));
typedef float v4f __attribute__((ext_vector_type(4)));

// fused: edge count (blocks [0,BE)) + weight cast/transpose (blocks [BE,BE+64))
__global__ __launch_bounds__(256) void k_count_wcast(const int* __restrict__ dst,
                                                     int* __restrict__ cnt, int nE,
                                                     int BE,
                                                     const float* __restrict__ W1,
                                                     const float* __restrict__ W2,
                                                     __half* __restrict__ Wt1,
                                                     __half* __restrict__ Wt2) {
    int b = blockIdx.x;
    if (b < BE) {
        int e = b * 256 + threadIdx.x;
        if (e < nE) atomicAdd(&cnt[dst[e]], 1);
    } else {
        int i = (b - BE) * 256 + threadIdx.x;   // 0..16383
        int k = i >> 7, c = i & 127;
        Wt1[c * 128 + k] = __float2half(W1[i]);
        Wt2[c * 128 + k] = __float2half(W2[i]);
    }
}

// scan stage 1 + fused dis = rsqrt(cnt+1)
__global__ __launch_bounds__(256) void k_scan_blk(const int* __restrict__ cnt,
                                                  float* __restrict__ dis,
                                                  int* __restrict__ excl,
                                                  int* __restrict__ blk_sum, int nN) {
    __shared__ int sm[256];
    const int t = threadIdx.x;
    int i = blockIdx.x * 256 + t;
    int v = (i < nN) ? cnt[i] : 0;
    if (i < nN) dis[i] = rsqrtf((float)v + 1.0f);
    sm[t] = v;
    __syncthreads();
#pragma unroll
    for (int off = 1; off < 256; off <<= 1) {
        int x = (t >= off) ? sm[t - off] : 0;
        __syncthreads();
        sm[t] += x;
        __syncthreads();
    }
    if (i < nN) excl[i] = sm[t] - v;
    if (t == 255) blk_sum[blockIdx.x] = sm[255];
}

// stage 2+3 fused: every block scans blk_sum (nB<=256) in LDS, then adds.
__global__ __launch_bounds__(256) void k_scan_add(const int* __restrict__ excl,
                                                  const int* __restrict__ blk_sum,
                                                  int* __restrict__ row_ptr,
                                                  int* __restrict__ cursor,
                                                  int nN, int nB) {
    __shared__ int sm[256];
    const int t = threadIdx.x;
    int v = (t < nB) ? blk_sum[t] : 0;
    sm[t] = v;
    __syncthreads();
#pragma unroll
    for (int off = 1; off < 256; off <<= 1) {
        int x = (t >= off) ? sm[t - off] : 0;
        __syncthreads();
        sm[t] += x;
        __syncthreads();
    }
    int i = blockIdx.x * 256 + t;
    if (i < nN) {
        int b = i >> 8;
        int off = sm[b] - blk_sum[b];
        int val = excl[i] + off;
        row_ptr[i] = val;
        cursor[i] = val;
    }
    if (i == 0) row_ptr[nN] = sm[255];
}

// register-accumulated pull of one node row (32 lanes x 4 halves = 128 cols),
// fp32 acc; includes the self term HWS[g].
__device__ __forceinline__ float4 gather_row(const float2* __restrict__ Hv,
                                             const int* __restrict__ row_ptr,
                                             const int* __restrict__ src_csr,
                                             int g, int f4) {
    int beg = row_ptr[g], end = row_ptr[g + 1];
    float2 r0 = Hv[(size_t)g * 32 + f4];
    float2 lo = __half22float2(*(__half2*)&r0.x);
    float2 hi = __half22float2(*(__half2*)&r0.y);
    float4 acc = make_float4(lo.x, lo.y, hi.x, hi.y);
    int e = beg;
    for (; e + 8 <= end; e += 8) {
        int s[8];
#pragma unroll
        for (int j = 0; j < 8; ++j) s[j] = src_csr[e + j];
        float2 r[8];
#pragma unroll
        for (int j = 0; j < 8; ++j) r[j] = Hv[(size_t)s[j] * 32 + f4];
#pragma unroll
        for (int j = 0; j < 8; ++j) {
            float2 l2 = __half22float2(*(__half2*)&r[j].x);
            float2 h2 = __half22float2(*(__half2*)&r[j].y);
            acc.x += l2.x; acc.y += l2.y; acc.z += h2.x; acc.w += h2.y;
        }
    }
    if (e + 4 <= end) {
        int s[4];
#pragma unroll
        for (int j = 0; j < 4; ++j) s[j] = src_csr[e + j];
        float2 r[4];
#pragma unroll
        for (int j = 0; j < 4; ++j) r[j] = Hv[(size_t)s[j] * 32 + f4];
#pragma unroll
        for (int j = 0; j < 4; ++j) {
            float2 l2 = __half22float2(*(__half2*)&r[j].x);
            float2 h2 = __half22float2(*(__half2*)&r[j].y);
            acc.x += l2.x; acc.y += l2.y; acc.z += h2.x; acc.w += h2.y;
        }
        e += 4;
    }
    for (; e < end; ++e) {
        float2 r = Hv[(size_t)src_csr[e] * 32 + f4];
        float2 l2 = __half22float2(*(__half2*)&r.x);
        float2 h2 = __half22float2(*(__half2*)&r.y);
        acc.x += l2.x; acc.y += l2.y; acc.z += h2.x; acc.w += h2.y;
    }
    return acc;
}

// FUSED dispatch: blocks [0,BG) = layer-1 MFMA GEMM; blocks [BG,BG+BEbin) =
// CSR binning. Independent work overlapped (bin is atomic-latency-bound,
// gemm is staging/MFMA-bound).
__global__ __launch_bounds__(256) void k_gemm_bin(const float* __restrict__ X32,
                                                  const __half* __restrict__ Wt,
                                                  const float* __restrict__ dis,
                                                  __half* __restrict__ HWS,
                                                  int nrows, int BG,
                                                  const int* __restrict__ src,
                                                  const int* __restrict__ dst,
                                                  int* __restrict__ cursor,
                                                  int* __restrict__ src_csr, int nE) {
    __shared__ __half xs[64 * 136];
    if (blockIdx.x >= BG) {
        // --- binning path ---
        int e = (blockIdx.x - BG) * 256 + threadIdx.x;
        if (e < nE) {
            int s = src[e], d = dst[e];
            int pos = atomicAdd(&cursor[d], 1);
            src_csr[pos] = s;
        }
        return;
    }

    // --- GEMM path ---
    const int t = threadIdx.x;
    const int row0 = blockIdx.x * 64;

#pragma unroll
    for (int i = 0; i < 8; ++i) {
        int f = t + i * 256;
        int r = f >> 5, k4 = f & 31;
        int gr = row0 + r;
        float4 v = make_float4(0.f, 0.f, 0.f, 0.f);
        if (gr < nrows) v = ((const float4*)X32)[(size_t)gr * 32 + k4];
        __half2 h01 = __float22half2_rn(make_float2(v.x, v.y));
        __half2 h23 = __float22half2_rn(make_float2(v.z, v.w));
        float2 packed;
        *(__half2*)&packed.x = h01;
        *(__half2*)&packed.y = h23;
        *(float2*)&xs[r * 136 + k4 * 4] = packed;
    }
    __syncthreads();

    const int w = t >> 6;
    const int l = t & 63;
    const int mrow = l & 15;
    const int kq = l >> 4;

    v8h a[4];
#pragma unroll
    for (int kk = 0; kk < 4; ++kk)
        a[kk] = *(const v8h*)&xs[(w * 16 + mrow) * 136 + kk * 32 + kq * 8];

    v4f acc[8];
#pragma unroll
    for (int c = 0; c < 8; ++c) acc[c] = (v4f){0.f, 0.f, 0.f, 0.f};

#pragma unroll
    for (int kk = 0; kk < 4; ++kk) {
#pragma unroll
        for (int c = 0; c < 8; ++c) {
            v8h b = *(const v8h*)&Wt[(size_t)(c * 16 + mrow) * 128 + kk * 32 + kq * 8];
            acc[c] = __builtin_amdgcn_mfma_f32_16x16x32_f16(a[kk], b, acc[c], 0, 0, 0);
        }
    }

    float dn[4];
#pragma unroll
    for (int r = 0; r < 4; ++r) {
        int grow = row0 + w * 16 + kq * 4 + r;
        dn[r] = (grow < nrows) ? dis[grow] : 0.f;
    }
#pragma unroll
    for (int c = 0; c < 8; ++c) {
#pragma unroll
        for (int r = 0; r < 4; ++r) {
            int grow = row0 + w * 16 + kq * 4 + r;
            if (grow < nrows)
                HWS[(size_t)grow * 128 + c * 16 + mrow] =
                    __float2half(acc[c][r] * dn[r]);
        }
    }
}

// FUSED layer-1 gather + layer-2 GEMM, 512 threads (R12 version: static
// 4 nodes per half-wave, no prefetch — VGPR 32 keeps 4 blocks/CU).
//   phase 1: 16 half-waves x 4 nodes: h1 = relu(dis*Σ HWS1 + b1) -> LDS fp16
//   phase 2: 8 MFMA waves; wave w owns rows (w&3)*16..+16, cols (w>>2)*64..+64
__global__ __launch_bounds__(512) void k_gather_gemm(const __half* __restrict__ HWS1,
                                                     const int* __restrict__ row_ptr,
                                                     const int* __restrict__ src_csr,
                                                     const float* __restrict__ dis,
                                                     const float* __restrict__ bias,
                                                     const __half* __restrict__ Wt,
                                                     __half* __restrict__ HWS2,
                                                     int nN) {
    __shared__ __half xs[64 * 136];
    const int t = threadIdx.x;
    const int row0 = blockIdx.x * 64;
    const int hw_id = t >> 5;   // half-wave 0..15
    const int f4 = t & 31;
    const float2* Hv = (const float2*)HWS1;
    const float4 bv = ((const float4*)bias)[f4];

#pragma unroll 1
    for (int i = 0; i < 4; ++i) {
        int lr = i * 16 + hw_id;
        int g = row0 + lr;
        float4 h = make_float4(0.f, 0.f, 0.f, 0.f);
        if (g < nN) {
            float4 acc = gather_row(Hv, row_ptr, src_csr, g, f4);
            float dn = dis[g];
            h.x = fmaxf(acc.x * dn + bv.x, 0.f);
            h.y = fmaxf(acc.y * dn + bv.y, 0.f);
            h.z = fmaxf(acc.z * dn + bv.z, 0.f);
            h.w = fmaxf(acc.w * dn + bv.w, 0.f);
        }
        __half2 h01 = __float22half2_rn(make_float2(h.x, h.y));
        __half2 h23 = __float22half2_rn(make_float2(h.z, h.w));
        float2 packed;
        *(__half2*)&packed.x = h01;
        *(__half2*)&packed.y = h23;
        *(float2*)&xs[lr * 136 + f4 * 4] = packed;
    }
    __syncthreads();

    const int w = t >> 6;        // wave 0..7
    const int l = t & 63;
    const int mrow = l & 15;
    const int kq = l >> 4;
    const int rgrp = (w & 3) * 16;   // row group
    const int cgrp = (w >> 2) * 4;   // col-tile group (4 tiles of 16)

    v8h a[4];
#pragma unroll
    for (int kk = 0; kk < 4; ++kk)
        a[kk] = *(const v8h*)&xs[(rgrp + mrow) * 136 + kk * 32 + kq * 8];

    v4f acc[4];
#pragma unroll
    for (int c = 0; c < 4; ++c) acc[c] = (v4f){0.f, 0.f, 0.f, 0.f};

#pragma unroll
    for (int kk = 0; kk < 4; ++kk) {
#pragma unroll
        for (int c = 0; c < 4; ++c) {
            v8h b = *(const v8h*)&Wt[(size_t)((cgrp + c) * 16 + mrow) * 128 + kk * 32 + kq * 8];
            acc[c] = __builtin_amdgcn_mfma_f32_16x16x32_f16(a[kk], b, acc[c], 0, 0, 0);
        }
    }

    float dn4[4];
#pragma unroll
    for (int r = 0; r < 4; ++r) {
        int grow = row0 + rgrp + kq * 4 + r;
        dn4[r] = (grow < nN) ? dis[grow] : 0.f;
    }
#pragma unroll
    for (int c = 0; c < 4; ++c) {
#pragma unroll
        for (int r = 0; r < 4; ++r) {
            int grow = row0 + rgrp + kq * 4 + r;
            if (grow < nN)
                HWS2[(size_t)grow * 128 + (cgrp + c) * 16 + mrow] =
                    __float2half(acc[c][r] * dn4[r]);
        }
    }
}

// FUSED layer-2 gather + layer-3 gemv:
//   hw3s[g] = dis[g] * dot(relu(dis[g]*Σ HWS2 + b2), W3)
__global__ __launch_bounds__(256) void k_gather_gemv(const __half* __restrict__ HWS2,
                                                     const int* __restrict__ row_ptr,
                                                     const int* __restrict__ src_csr,
                                                     const float* __restrict__ dis,
                                                     const float* __restrict__ bias,
                                                     const float* __restrict__ W3,
                                                     float* __restrict__ hw3s, int nN) {
    int g = blockIdx.x * 8 + (threadIdx.x >> 5);
    if (g >= nN) return;
    int f4 = threadIdx.x & 31;
    float4 acc = gather_row((const float2*)HWS2, row_ptr, src_csr, g, f4);
    float dn = dis[g];
    float4 bv = ((const float4*)bias)[f4];
    float4 w  = ((const float4*)W3)[f4];
    float sum = fmaxf(acc.x * dn + bv.x, 0.f) * w.x
              + fmaxf(acc.y * dn + bv.y, 0.f) * w.y
              + fmaxf(acc.z * dn + bv.z, 0.f) * w.z
              + fmaxf(acc.w * dn + bv.w, 0.f) * w.w;
#pragma unroll
    for (int off = 16; off > 0; off >>= 1) sum += __shfl_down(sum, off, 32);
    if (f4 == 0) hw3s[g] = sum * dn;
}

// scalar pull-aggregation + final relu -> d_out
__global__ __launch_bounds__(256) void k_gather3(const float* __restrict__ hw3s,
                                                 const int* __restrict__ row_ptr,
                                                 const int* __restrict__ src_csr,
                                                 const float* __restrict__ dis,
                                                 const float* __restrict__ b3,
                                                 float* __restrict__ out, int nN) {
    int i = blockIdx.x * 256 + threadIdx.x;
    if (i >= nN) return;
    float acc = hw3s[i];
    int beg = row_ptr[i], end = row_ptr[i + 1];
    for (int e = beg; e < end; ++e) acc += hw3s[src_csr[e]];
    out[i] = fmaxf(acc * dis[i] + b3[0], 0.f);
}

extern "C" void kernel_launch(void* const* d_in, const int* in_sizes, int n_in,
                              void* d_out, int out_size, void* d_ws, size_t ws_size,
                              hipStream_t stream) {
    const float* x  = (const float*)d_in[0];
    const int*   ei = (const int*)d_in[1];
    const float* W1 = (const float*)d_in[2];
    const float* b1 = (const float*)d_in[3];
    const float* W2 = (const float*)d_in[4];
    const float* b2 = (const float*)d_in[5];
    const float* W3 = (const float*)d_in[6];
    const float* b3 = (const float*)d_in[7];

    const int nN = in_sizes[0] / 128;
    const int nE = in_sizes[1] / 2;
    const int* src = ei;
    const int* dst = ei + nE;

    const int nB = (nN + 255) / 256;   // scan blocks (<=256)

    // workspace layout
    char* p = (char*)d_ws;
    int*    cnt      = (int*)p;           p += (size_t)nN * 4;
    int*    cursor   = (int*)p;           p += (size_t)nN * 4;
    int*    excl     = (int*)p;           p += (size_t)nN * 4;
    int*    blk_sum  = (int*)p;           p += (size_t)(nB + 1) * 4;
    int*    row_ptr  = (int*)p;           p += (size_t)(nN + 1) * 4;
    int*    src_csr  = (int*)p;           p += (size_t)nE * 4;
    float*  dis      = (float*)p;         p += (size_t)nN * 4;
    float*  hw3s     = (float*)p;         p += (size_t)nN * 4;
    p = (char*)(((uintptr_t)p + 255) & ~(uintptr_t)255);
    __half* Wt1      = (__half*)p;        p += (size_t)128 * 128 * 2;
    __half* Wt2      = (__half*)p;        p += (size_t)128 * 128 * 2;
    __half* bufA     = (__half*)p;        p += (size_t)nN * 128 * 2;  // HWS1
    p = (char*)(((uintptr_t)p + 255) & ~(uintptr_t)255);
    __half* bufB     = (__half*)p;        p += (size_t)nN * 128 * 2;  // HWS2

    const int BE  = (nE + 255) / 256;
    const int BN  = (nN + 255) / 256;
    const int BG  = (nN + 63) / 64;
    const int BGA = (nN + 7) / 8;

    // --- CSR build + norms + weight cast ---
    hipMemsetAsync(cnt, 0, (size_t)nN * sizeof(int), stream);
    k_count_wcast<<<BE + 64, 256, 0, stream>>>(dst, cnt, nE, BE, W1, W2, Wt1, Wt2);
    k_scan_blk<<<nB, 256, 0, stream>>>(cnt, dis, excl, blk_sum, nN);
    k_scan_add<<<nB, 256, 0, stream>>>(excl, blk_sum, row_ptr, cursor, nN, nB);

    // --- layer-1 GEMM (blocks [0,BG)) overlapped with CSR binning ---
    k_gemm_bin<<<BG + BE, 256, 0, stream>>>(x, Wt1, dis, bufA, nN, BG,
                                            src, dst, cursor, src_csr, nE);

    // --- fused layer-1 gather + layer-2 GEMM: HWS1 -> HWS2 (512 thr) ---
    k_gather_gemm<<<BG, 512, 0, stream>>>(bufA, row_ptr, src_csr, dis, b1, Wt2,
                                          bufB, nN);

    // --- fused layer-2 gather + layer-3 gemv: HWS2 -> hw3s ---
    k_gather_gemv<<<BGA, 256, 0, stream>>>(bufB, row_ptr, src_csr, dis, b2, W3,
                                           hw3s, nN);

    // --- layer-3 scalar gather -> d_out ---
    k_gather3<<<BN, 256, 0, stream>>>(hw3s, row_ptr, src_csr, dis, b3,
                                      (float*)d_out, nN);
}

// Round 15
// 217.300 us; speedup vs baseline: 1.2047x; 1.0821x over previous
//
#include <hip/hip_runtime.h>
#include <hip/hip_fp16.h>

// ---------------------------------------------------------------------------
// 3-layer GCN, CSR-gather, fp16 dataflow + MFMA GEMM, fused pipeline:
//   count+wcast:  cnt histogram (stores per-edge rank!) || Wt cast
//   gemm1+bin:    HWS1 = half(dis*(x@W1))  ||  atomic-free CSR binning via rank
//   gather+gemm2: h1 = relu(dis*Σ HWS1 + b1) -> LDS -> HWS2 = half(dis*(h1@W2))
//   gather+gemv:  hw3s = dis * dot(relu(dis*Σ HWS2 + b2), W3)
//   gather3:      out = relu(dis*Σ hw3s + b3)
// Lessons: R4/R5 never force __launch_bounds__ min-waves (VGPR cap 256/w ->
// spills). R7/R8: gather is bytes-below-L2 bound (fp16 halves it). R11/R12:
// fused gather needs 512-thr blocks. R13: keep hot kernel VGPR<=32 (tier at
// 64 halves occupancy). R14: bin was atomic-latency-bound -> rank trick.
// ---------------------------------------------------------------------------

typedef _Float16 v8h __attribute__((ext_vector_type(8)));
typedef float v4f __attribute__((ext_vector_type(4)));

// fused: edge count + rank record (blocks [0,BE)) + weight cast (blocks >=BE)
__global__ __launch_bounds__(256) void k_count_wcast(const int* __restrict__ dst,
                                                     int* __restrict__ cnt,
                                                     int* __restrict__ rank, int nE,
                                                     int BE,
                                                     const float* __restrict__ W1,
                                                     const float* __restrict__ W2,
                                                     __half* __restrict__ Wt1,
                                                     __half* __restrict__ Wt2) {
    int b = blockIdx.x;
    if (b < BE) {
        int e = b * 256 + threadIdx.x;
        if (e < nE) rank[e] = atomicAdd(&cnt[dst[e]], 1);
    } else {
        int i = (b - BE) * 256 + threadIdx.x;   // 0..16383
        int k = i >> 7, c = i & 127;
        Wt1[c * 128 + k] = __float2half(W1[i]);
        Wt2[c * 128 + k] = __float2half(W2[i]);
    }
}

// scan stage 1 + fused dis = rsqrt(cnt+1)
__global__ __launch_bounds__(256) void k_scan_blk(const int* __restrict__ cnt,
                                                  float* __restrict__ dis,
                                                  int* __restrict__ excl,
                                                  int* __restrict__ blk_sum, int nN) {
    __shared__ int sm[256];
    const int t = threadIdx.x;
    int i = blockIdx.x * 256 + t;
    int v = (i < nN) ? cnt[i] : 0;
    if (i < nN) dis[i] = rsqrtf((float)v + 1.0f);
    sm[t] = v;
    __syncthreads();
#pragma unroll
    for (int off = 1; off < 256; off <<= 1) {
        int x = (t >= off) ? sm[t - off] : 0;
        __syncthreads();
        sm[t] += x;
        __syncthreads();
    }
    if (i < nN) excl[i] = sm[t] - v;
    if (t == 255) blk_sum[blockIdx.x] = sm[255];
}

// stage 2+3 fused: every block scans blk_sum (nB<=256) in LDS, then adds.
__global__ __launch_bounds__(256) void k_scan_add(const int* __restrict__ excl,
                                                  const int* __restrict__ blk_sum,
                                                  int* __restrict__ row_ptr,
                                                  int nN, int nB) {
    __shared__ int sm[256];
    const int t = threadIdx.x;
    int v = (t < nB) ? blk_sum[t] : 0;
    sm[t] = v;
    __syncthreads();
#pragma unroll
    for (int off = 1; off < 256; off <<= 1) {
        int x = (t >= off) ? sm[t - off] : 0;
        __syncthreads();
        sm[t] += x;
        __syncthreads();
    }
    int i = blockIdx.x * 256 + t;
    if (i < nN) {
        int b = i >> 8;
        row_ptr[i] = excl[i] + sm[b] - blk_sum[b];
    }
    if (i == 0) row_ptr[nN] = sm[255];
}

// register-accumulated pull of one node row (32 lanes x 4 halves = 128 cols),
// fp32 acc; includes the self term HWS[g].
__device__ __forceinline__ float4 gather_row(const float2* __restrict__ Hv,
                                             const int* __restrict__ row_ptr,
                                             const int* __restrict__ src_csr,
                                             int g, int f4) {
    int beg = row_ptr[g], end = row_ptr[g + 1];
    float2 r0 = Hv[(size_t)g * 32 + f4];
    float2 lo = __half22float2(*(__half2*)&r0.x);
    float2 hi = __half22float2(*(__half2*)&r0.y);
    float4 acc = make_float4(lo.x, lo.y, hi.x, hi.y);
    int e = beg;
    for (; e + 8 <= end; e += 8) {
        int s[8];
#pragma unroll
        for (int j = 0; j < 8; ++j) s[j] = src_csr[e + j];
        float2 r[8];
#pragma unroll
        for (int j = 0; j < 8; ++j) r[j] = Hv[(size_t)s[j] * 32 + f4];
#pragma unroll
        for (int j = 0; j < 8; ++j) {
            float2 l2 = __half22float2(*(__half2*)&r[j].x);
            float2 h2 = __half22float2(*(__half2*)&r[j].y);
            acc.x += l2.x; acc.y += l2.y; acc.z += h2.x; acc.w += h2.y;
        }
    }
    if (e + 4 <= end) {
        int s[4];
#pragma unroll
        for (int j = 0; j < 4; ++j) s[j] = src_csr[e + j];
        float2 r[4];
#pragma unroll
        for (int j = 0; j < 4; ++j) r[j] = Hv[(size_t)s[j] * 32 + f4];
#pragma unroll
        for (int j = 0; j < 4; ++j) {
            float2 l2 = __half22float2(*(__half2*)&r[j].x);
            float2 h2 = __half22float2(*(__half2*)&r[j].y);
            acc.x += l2.x; acc.y += l2.y; acc.z += h2.x; acc.w += h2.y;
        }
        e += 4;
    }
    for (; e < end; ++e) {
        float2 r = Hv[(size_t)src_csr[e] * 32 + f4];
        float2 l2 = __half22float2(*(__half2*)&r.x);
        float2 h2 = __half22float2(*(__half2*)&r.y);
        acc.x += l2.x; acc.y += l2.y; acc.z += h2.x; acc.w += h2.y;
    }
    return acc;
}

// FUSED dispatch: blocks [0,BG) = layer-1 MFMA GEMM; blocks >=BG = CSR bin.
// Bin path is atomic-free: pos = row_ptr[dst] + rank (recorded during count).
__global__ __launch_bounds__(256) void k_gemm_bin(const float* __restrict__ X32,
                                                  const __half* __restrict__ Wt,
                                                  const float* __restrict__ dis,
                                                  __half* __restrict__ HWS,
                                                  int nrows, int BG,
                                                  const int* __restrict__ src,
                                                  const int* __restrict__ dst,
                                                  const int* __restrict__ rank,
                                                  const int* __restrict__ row_ptr,
                                                  int* __restrict__ src_csr, int nE) {
    __shared__ __half xs[64 * 136];
    if (blockIdx.x >= BG) {
        // --- binning path (no atomics) ---
        int e = (blockIdx.x - BG) * 256 + threadIdx.x;
        if (e < nE) {
            int d = dst[e];
            src_csr[row_ptr[d] + rank[e]] = src[e];
        }
        return;
    }

    // --- GEMM path ---
    const int t = threadIdx.x;
    const int row0 = blockIdx.x * 64;

#pragma unroll
    for (int i = 0; i < 8; ++i) {
        int f = t + i * 256;
        int r = f >> 5, k4 = f & 31;
        int gr = row0 + r;
        float4 v = make_float4(0.f, 0.f, 0.f, 0.f);
        if (gr < nrows) v = ((const float4*)X32)[(size_t)gr * 32 + k4];
        __half2 h01 = __float22half2_rn(make_float2(v.x, v.y));
        __half2 h23 = __float22half2_rn(make_float2(v.z, v.w));
        float2 packed;
        *(__half2*)&packed.x = h01;
        *(__half2*)&packed.y = h23;
        *(float2*)&xs[r * 136 + k4 * 4] = packed;
    }
    __syncthreads();

    const int w = t >> 6;
    const int l = t & 63;
    const int mrow = l & 15;
    const int kq = l >> 4;

    v8h a[4];
#pragma unroll
    for (int kk = 0; kk < 4; ++kk)
        a[kk] = *(const v8h*)&xs[(w * 16 + mrow) * 136 + kk * 32 + kq * 8];

    v4f acc[8];
#pragma unroll
    for (int c = 0; c < 8; ++c) acc[c] = (v4f){0.f, 0.f, 0.f, 0.f};

#pragma unroll
    for (int kk = 0; kk < 4; ++kk) {
#pragma unroll
        for (int c = 0; c < 8; ++c) {
            v8h b = *(const v8h*)&Wt[(size_t)(c * 16 + mrow) * 128 + kk * 32 + kq * 8];
            acc[c] = __builtin_amdgcn_mfma_f32_16x16x32_f16(a[kk], b, acc[c], 0, 0, 0);
        }
    }

    float dn[4];
#pragma unroll
    for (int r = 0; r < 4; ++r) {
        int grow = row0 + w * 16 + kq * 4 + r;
        dn[r] = (grow < nrows) ? dis[grow] : 0.f;
    }
#pragma unroll
    for (int c = 0; c < 8; ++c) {
#pragma unroll
        for (int r = 0; r < 4; ++r) {
            int grow = row0 + w * 16 + kq * 4 + r;
            if (grow < nrows)
                HWS[(size_t)grow * 128 + c * 16 + mrow] =
                    __float2half(acc[c][r] * dn[r]);
        }
    }
}

// FUSED layer-1 gather + layer-2 GEMM, 512 threads (static 4 nodes/half-wave,
// no prefetch — VGPR 32 keeps 4 blocks/CU).
__global__ __launch_bounds__(512) void k_gather_gemm(const __half* __restrict__ HWS1,
                                                     const int* __restrict__ row_ptr,
                                                     const int* __restrict__ src_csr,
                                                     const float* __restrict__ dis,
                                                     const float* __restrict__ bias,
                                                     const __half* __restrict__ Wt,
                                                     __half* __restrict__ HWS2,
                                                     int nN) {
    __shared__ __half xs[64 * 136];
    const int t = threadIdx.x;
    const int row0 = blockIdx.x * 64;
    const int hw_id = t >> 5;   // half-wave 0..15
    const int f4 = t & 31;
    const float2* Hv = (const float2*)HWS1;
    const float4 bv = ((const float4*)bias)[f4];

#pragma unroll 1
    for (int i = 0; i < 4; ++i) {
        int lr = i * 16 + hw_id;
        int g = row0 + lr;
        float4 h = make_float4(0.f, 0.f, 0.f, 0.f);
        if (g < nN) {
            float4 acc = gather_row(Hv, row_ptr, src_csr, g, f4);
            float dn = dis[g];
            h.x = fmaxf(acc.x * dn + bv.x, 0.f);
            h.y = fmaxf(acc.y * dn + bv.y, 0.f);
            h.z = fmaxf(acc.z * dn + bv.z, 0.f);
            h.w = fmaxf(acc.w * dn + bv.w, 0.f);
        }
        __half2 h01 = __float22half2_rn(make_float2(h.x, h.y));
        __half2 h23 = __float22half2_rn(make_float2(h.z, h.w));
        float2 packed;
        *(__half2*)&packed.x = h01;
        *(__half2*)&packed.y = h23;
        *(float2*)&xs[lr * 136 + f4 * 4] = packed;
    }
    __syncthreads();

    const int w = t >> 6;        // wave 0..7
    const int l = t & 63;
    const int mrow = l & 15;
    const int kq = l >> 4;
    const int rgrp = (w & 3) * 16;   // row group
    const int cgrp = (w >> 2) * 4;   // col-tile group (4 tiles of 16)

    v8h a[4];
#pragma unroll
    for (int kk = 0; kk < 4; ++kk)
        a[kk] = *(const v8h*)&xs[(rgrp + mrow) * 136 + kk * 32 + kq * 8];

    v4f acc[4];
#pragma unroll
    for (int c = 0; c < 4; ++c) acc[c] = (v4f){0.f, 0.f, 0.f, 0.f};

#pragma unroll
    for (int kk = 0; kk < 4; ++kk) {
#pragma unroll
        for (int c = 0; c < 4; ++c) {
            v8h b = *(const v8h*)&Wt[(size_t)((cgrp + c) * 16 + mrow) * 128 + kk * 32 + kq * 8];
            acc[c] = __builtin_amdgcn_mfma_f32_16x16x32_f16(a[kk], b, acc[c], 0, 0, 0);
        }
    }

    float dn4[4];
#pragma unroll
    for (int r = 0; r < 4; ++r) {
        int grow = row0 + rgrp + kq * 4 + r;
        dn4[r] = (grow < nN) ? dis[grow] : 0.f;
    }
#pragma unroll
    for (int c = 0; c < 4; ++c) {
#pragma unroll
        for (int r = 0; r < 4; ++r) {
            int grow = row0 + rgrp + kq * 4 + r;
            if (grow < nN)
                HWS2[(size_t)grow * 128 + (cgrp + c) * 16 + mrow] =
                    __float2half(acc[c][r] * dn4[r]);
        }
    }
}

// FUSED layer-2 gather + layer-3 gemv:
//   hw3s[g] = dis[g] * dot(relu(dis[g]*Σ HWS2 + b2), W3)
__global__ __launch_bounds__(256) void k_gather_gemv(const __half* __restrict__ HWS2,
                                                     const int* __restrict__ row_ptr,
                                                     const int* __restrict__ src_csr,
                                                     const float* __restrict__ dis,
                                                     const float* __restrict__ bias,
                                                     const float* __restrict__ W3,
                                                     float* __restrict__ hw3s, int nN) {
    int g = blockIdx.x * 8 + (threadIdx.x >> 5);
    if (g >= nN) return;
    int f4 = threadIdx.x & 31;
    float4 acc = gather_row((const float2*)HWS2, row_ptr, src_csr, g, f4);
    float dn = dis[g];
    float4 bv = ((const float4*)bias)[f4];
    float4 w  = ((const float4*)W3)[f4];
    float sum = fmaxf(acc.x * dn + bv.x, 0.f) * w.x
              + fmaxf(acc.y * dn + bv.y, 0.f) * w.y
              + fmaxf(acc.z * dn + bv.z, 0.f) * w.z
              + fmaxf(acc.w * dn + bv.w, 0.f) * w.w;
#pragma unroll
    for (int off = 16; off > 0; off >>= 1) sum += __shfl_down(sum, off, 32);
    if (f4 == 0) hw3s[g] = sum * dn;
}

// scalar pull-aggregation + final relu -> d_out
__global__ __launch_bounds__(256) void k_gather3(const float* __restrict__ hw3s,
                                                 const int* __restrict__ row_ptr,
                                                 const int* __restrict__ src_csr,
                                                 const float* __restrict__ dis,
                                                 const float* __restrict__ b3,
                                                 float* __restrict__ out, int nN) {
    int i = blockIdx.x * 256 + threadIdx.x;
    if (i >= nN) return;
    float acc = hw3s[i];
    int beg = row_ptr[i], end = row_ptr[i + 1];
    for (int e = beg; e < end; ++e) acc += hw3s[src_csr[e]];
    out[i] = fmaxf(acc * dis[i] + b3[0], 0.f);
}

extern "C" void kernel_launch(void* const* d_in, const int* in_sizes, int n_in,
                              void* d_out, int out_size, void* d_ws, size_t ws_size,
                              hipStream_t stream) {
    const float* x  = (const float*)d_in[0];
    const int*   ei = (const int*)d_in[1];
    const float* W1 = (const float*)d_in[2];
    const float* b1 = (const float*)d_in[3];
    const float* W2 = (const float*)d_in[4];
    const float* b2 = (const float*)d_in[5];
    const float* W3 = (const float*)d_in[6];
    const float* b3 = (const float*)d_in[7];

    const int nN = in_sizes[0] / 128;
    const int nE = in_sizes[1] / 2;
    const int* src = ei;
    const int* dst = ei + nE;

    const int nB = (nN + 255) / 256;   // scan blocks (<=256)

    // workspace layout
    char* p = (char*)d_ws;
    int*    cnt      = (int*)p;           p += (size_t)nN * 4;
    int*    excl     = (int*)p;           p += (size_t)nN * 4;
    int*    blk_sum  = (int*)p;           p += (size_t)(nB + 1) * 4;
    int*    row_ptr  = (int*)p;           p += (size_t)(nN + 1) * 4;
    int*    rank     = (int*)p;           p += (size_t)nE * 4;
    int*    src_csr  = (int*)p;           p += (size_t)nE * 4;
    float*  dis      = (float*)p;         p += (size_t)nN * 4;
    float*  hw3s     = (float*)p;         p += (size_t)nN * 4;
    p = (char*)(((uintptr_t)p + 255) & ~(uintptr_t)255);
    __half* Wt1      = (__half*)p;        p += (size_t)128 * 128 * 2;
    __half* Wt2      = (__half*)p;        p += (size_t)128 * 128 * 2;
    __half* bufA     = (__half*)p;        p += (size_t)nN * 128 * 2;  // HWS1
    p = (char*)(((uintptr_t)p + 255) & ~(uintptr_t)255);
    __half* bufB     = (__half*)p;        p += (size_t)nN * 128 * 2;  // HWS2

    const int BE  = (nE + 255) / 256;
    const int BN  = (nN + 255) / 256;
    const int BG  = (nN + 63) / 64;
    const int BGA = (nN + 7) / 8;

    // --- CSR build + norms + weight cast ---
    hipMemsetAsync(cnt, 0, (size_t)nN * sizeof(int), stream);
    k_count_wcast<<<BE + 64, 256, 0, stream>>>(dst, cnt, rank, nE, BE,
                                               W1, W2, Wt1, Wt2);
    k_scan_blk<<<nB, 256, 0, stream>>>(cnt, dis, excl, blk_sum, nN);
    k_scan_add<<<nB, 256, 0, stream>>>(excl, blk_sum, row_ptr, nN, nB);

    // --- layer-1 GEMM (blocks [0,BG)) overlapped with atomic-free binning ---
    k_gemm_bin<<<BG + BE, 256, 0, stream>>>(x, Wt1, dis, bufA, nN, BG,
                                            src, dst, rank, row_ptr, src_csr, nE);

    // --- fused layer-1 gather + layer-2 GEMM: HWS1 -> HWS2 (512 thr) ---
    k_gather_gemm<<<BG, 512, 0, stream>>>(bufA, row_ptr, src_csr, dis, b1, Wt2,
                                          bufB, nN);

    // --- fused layer-2 gather + layer-3 gemv: HWS2 -> hw3s ---
    k_gather_gemv<<<BGA, 256, 0, stream>>>(bufB, row_ptr, src_csr, dis, b2, W3,
                                           hw3s, nN);

    // --- layer-3 scalar gather -> d_out ---
    k_gather3<<<BN, 256, 0, stream>>>(hw3s, row_ptr, src_csr, dis, b3,
                                      (float*)d_out, nN);
}

// Round 16
// 216.923 us; speedup vs baseline: 1.2068x; 1.0017x over previous
//
#include <hip/hip_runtime.h>
#include <hip/hip_fp16.h>

// ---------------------------------------------------------------------------
// 3-layer GCN, CSR-gather, fp16 dataflow + MFMA GEMM, fused pipeline:
//   count+wcast:  cnt histogram (stores per-edge rank!) || Wt cast
//   gemm1+bin:    HWS1 = half(dis*(x@W1))  ||  atomic-free CSR binning via rank
//   gather+gemm2: h1 = relu(dis*Σ HWS1 + b1) -> LDS -> HWS2 = half(dis*(h1@W2))
//                 [512 thr; DYNAMIC node queue (R16) -- no static straggler]
//   gather+gemv:  hw3s = dis * dot(relu(dis*Σ HWS2 + b2), W3)
//   gather3:      out = relu(dis*Σ hw3s + b3)
// Lessons: R4/R5 never force __launch_bounds__ min-waves (VGPR cap 256/w ->
// spills). R7/R8: gather is bytes-below-L2 bound (fp16 halves it). R11/R12:
// fused gather needs 512-thr blocks. R13: keep hot kernel VGPR<64 (tier
// halves occupancy); prefetch was the R13 regression, not the queue.
// R14/R15: bin atomics -> rank trick.
// ---------------------------------------------------------------------------

typedef _Float16 v8h __attribute__((ext_vector_type(8)));
typedef float v4f __attribute__((ext_vector_type(4)));

// fused: edge count + rank record (blocks [0,BE)) + weight cast (blocks >=BE)
__global__ __launch_bounds__(256) void k_count_wcast(const int* __restrict__ dst,
                                                     int* __restrict__ cnt,
                                                     int* __restrict__ rank, int nE,
                                                     int BE,
                                                     const float* __restrict__ W1,
                                                     const float* __restrict__ W2,
                                                     __half* __restrict__ Wt1,
                                                     __half* __restrict__ Wt2) {
    int b = blockIdx.x;
    if (b < BE) {
        int e = b * 256 + threadIdx.x;
        if (e < nE) rank[e] = atomicAdd(&cnt[dst[e]], 1);
    } else {
        int i = (b - BE) * 256 + threadIdx.x;   // 0..16383
        int k = i >> 7, c = i & 127;
        Wt1[c * 128 + k] = __float2half(W1[i]);
        Wt2[c * 128 + k] = __float2half(W2[i]);
    }
}

// scan stage 1 + fused dis = rsqrt(cnt+1)
__global__ __launch_bounds__(256) void k_scan_blk(const int* __restrict__ cnt,
                                                  float* __restrict__ dis,
                                                  int* __restrict__ excl,
                                                  int* __restrict__ blk_sum, int nN) {
    __shared__ int sm[256];
    const int t = threadIdx.x;
    int i = blockIdx.x * 256 + t;
    int v = (i < nN) ? cnt[i] : 0;
    if (i < nN) dis[i] = rsqrtf((float)v + 1.0f);
    sm[t] = v;
    __syncthreads();
#pragma unroll
    for (int off = 1; off < 256; off <<= 1) {
        int x = (t >= off) ? sm[t - off] : 0;
        __syncthreads();
        sm[t] += x;
        __syncthreads();
    }
    if (i < nN) excl[i] = sm[t] - v;
    if (t == 255) blk_sum[blockIdx.x] = sm[255];
}

// stage 2+3 fused: every block scans blk_sum (nB<=256) in LDS, then adds.
__global__ __launch_bounds__(256) void k_scan_add(const int* __restrict__ excl,
                                                  const int* __restrict__ blk_sum,
                                                  int* __restrict__ row_ptr,
                                                  int nN, int nB) {
    __shared__ int sm[256];
    const int t = threadIdx.x;
    int v = (t < nB) ? blk_sum[t] : 0;
    sm[t] = v;
    __syncthreads();
#pragma unroll
    for (int off = 1; off < 256; off <<= 1) {
        int x = (t >= off) ? sm[t - off] : 0;
        __syncthreads();
        sm[t] += x;
        __syncthreads();
    }
    int i = blockIdx.x * 256 + t;
    if (i < nN) {
        int b = i >> 8;
        row_ptr[i] = excl[i] + sm[b] - blk_sum[b];
    }
    if (i == 0) row_ptr[nN] = sm[255];
}

// register-accumulated pull of one node row (32 lanes x 4 halves = 128 cols),
// fp32 acc; includes the self term HWS[g].
__device__ __forceinline__ float4 gather_row(const float2* __restrict__ Hv,
                                             const int* __restrict__ row_ptr,
                                             const int* __restrict__ src_csr,
                                             int g, int f4) {
    int beg = row_ptr[g], end = row_ptr[g + 1];
    float2 r0 = Hv[(size_t)g * 32 + f4];
    float2 lo = __half22float2(*(__half2*)&r0.x);
    float2 hi = __half22float2(*(__half2*)&r0.y);
    float4 acc = make_float4(lo.x, lo.y, hi.x, hi.y);
    int e = beg;
    for (; e + 8 <= end; e += 8) {
        int s[8];
#pragma unroll
        for (int j = 0; j < 8; ++j) s[j] = src_csr[e + j];
        float2 r[8];
#pragma unroll
        for (int j = 0; j < 8; ++j) r[j] = Hv[(size_t)s[j] * 32 + f4];
#pragma unroll
        for (int j = 0; j < 8; ++j) {
            float2 l2 = __half22float2(*(__half2*)&r[j].x);
            float2 h2 = __half22float2(*(__half2*)&r[j].y);
            acc.x += l2.x; acc.y += l2.y; acc.z += h2.x; acc.w += h2.y;
        }
    }
    if (e + 4 <= end) {
        int s[4];
#pragma unroll
        for (int j = 0; j < 4; ++j) s[j] = src_csr[e + j];
        float2 r[4];
#pragma unroll
        for (int j = 0; j < 4; ++j) r[j] = Hv[(size_t)s[j] * 32 + f4];
#pragma unroll
        for (int j = 0; j < 4; ++j) {
            float2 l2 = __half22float2(*(__half2*)&r[j].x);
            float2 h2 = __half22float2(*(__half2*)&r[j].y);
            acc.x += l2.x; acc.y += l2.y; acc.z += h2.x; acc.w += h2.y;
        }
        e += 4;
    }
    for (; e < end; ++e) {
        float2 r = Hv[(size_t)src_csr[e] * 32 + f4];
        float2 l2 = __half22float2(*(__half2*)&r.x);
        float2 h2 = __half22float2(*(__half2*)&r.y);
        acc.x += l2.x; acc.y += l2.y; acc.z += h2.x; acc.w += h2.y;
    }
    return acc;
}

// FUSED dispatch: blocks [0,BG) = layer-1 MFMA GEMM; blocks >=BG = CSR bin.
// Bin path is atomic-free: pos = row_ptr[dst] + rank (recorded during count).
__global__ __launch_bounds__(256) void k_gemm_bin(const float* __restrict__ X32,
                                                  const __half* __restrict__ Wt,
                                                  const float* __restrict__ dis,
                                                  __half* __restrict__ HWS,
                                                  int nrows, int BG,
                                                  const int* __restrict__ src,
                                                  const int* __restrict__ dst,
                                                  const int* __restrict__ rank,
                                                  const int* __restrict__ row_ptr,
                                                  int* __restrict__ src_csr, int nE) {
    __shared__ __half xs[64 * 136];
    if (blockIdx.x >= BG) {
        // --- binning path (no atomics) ---
        int e = (blockIdx.x - BG) * 256 + threadIdx.x;
        if (e < nE) {
            int d = dst[e];
            src_csr[row_ptr[d] + rank[e]] = src[e];
        }
        return;
    }

    // --- GEMM path ---
    const int t = threadIdx.x;
    const int row0 = blockIdx.x * 64;

#pragma unroll
    for (int i = 0; i < 8; ++i) {
        int f = t + i * 256;
        int r = f >> 5, k4 = f & 31;
        int gr = row0 + r;
        float4 v = make_float4(0.f, 0.f, 0.f, 0.f);
        if (gr < nrows) v = ((const float4*)X32)[(size_t)gr * 32 + k4];
        __half2 h01 = __float22half2_rn(make_float2(v.x, v.y));
        __half2 h23 = __float22half2_rn(make_float2(v.z, v.w));
        float2 packed;
        *(__half2*)&packed.x = h01;
        *(__half2*)&packed.y = h23;
        *(float2*)&xs[r * 136 + k4 * 4] = packed;
    }
    __syncthreads();

    const int w = t >> 6;
    const int l = t & 63;
    const int mrow = l & 15;
    const int kq = l >> 4;

    v8h a[4];
#pragma unroll
    for (int kk = 0; kk < 4; ++kk)
        a[kk] = *(const v8h*)&xs[(w * 16 + mrow) * 136 + kk * 32 + kq * 8];

    v4f acc[8];
#pragma unroll
    for (int c = 0; c < 8; ++c) acc[c] = (v4f){0.f, 0.f, 0.f, 0.f};

#pragma unroll
    for (int kk = 0; kk < 4; ++kk) {
#pragma unroll
        for (int c = 0; c < 8; ++c) {
            v8h b = *(const v8h*)&Wt[(size_t)(c * 16 + mrow) * 128 + kk * 32 + kq * 8];
            acc[c] = __builtin_amdgcn_mfma_f32_16x16x32_f16(a[kk], b, acc[c], 0, 0, 0);
        }
    }

    float dn[4];
#pragma unroll
    for (int r = 0; r < 4; ++r) {
        int grow = row0 + w * 16 + kq * 4 + r;
        dn[r] = (grow < nrows) ? dis[grow] : 0.f;
    }
#pragma unroll
    for (int c = 0; c < 8; ++c) {
#pragma unroll
        for (int r = 0; r < 4; ++r) {
            int grow = row0 + w * 16 + kq * 4 + r;
            if (grow < nrows)
                HWS[(size_t)grow * 128 + c * 16 + mrow] =
                    __float2half(acc[c][r] * dn[r]);
        }
    }
}

// FUSED layer-1 gather + layer-2 GEMM, 512 threads.
//   phase 1: 16 half-waves pull node slots from an LDS queue (straggler fix;
//            VGPR must stay <64 — no prefetch, R13 lesson)
//   phase 2: 8 MFMA waves; wave w: rows (w&3)*16..+16, col-tiles (w>>2)*4..+4
__global__ __launch_bounds__(512) void k_gather_gemm(const __half* __restrict__ HWS1,
                                                     const int* __restrict__ row_ptr,
                                                     const int* __restrict__ src_csr,
                                                     const float* __restrict__ dis,
                                                     const float* __restrict__ bias,
                                                     const __half* __restrict__ Wt,
                                                     __half* __restrict__ HWS2,
                                                     int nN) {
    __shared__ __half xs[64 * 136];
    __shared__ int q;
    const int t = threadIdx.x;
    const int row0 = blockIdx.x * 64;
    const int f4 = t & 31;
    const float2* Hv = (const float2*)HWS1;
    const float4 bv = ((const float4*)bias)[f4];

    if (t == 0) q = 0;
    __syncthreads();

    const int l = t & 63;
    const int bcast_lane = (l >> 5) << 5;   // lane 0 or 32 of this wave
    for (;;) {
        int lr = 0;
        if (f4 == 0) lr = atomicAdd(&q, 1);
        lr = __shfl(lr, bcast_lane, 64);
        if (lr >= 64) break;
        int g = row0 + lr;
        float4 h = make_float4(0.f, 0.f, 0.f, 0.f);
        if (g < nN) {
            float4 acc = gather_row(Hv, row_ptr, src_csr, g, f4);
            float dn = dis[g];
            h.x = fmaxf(acc.x * dn + bv.x, 0.f);
            h.y = fmaxf(acc.y * dn + bv.y, 0.f);
            h.z = fmaxf(acc.z * dn + bv.z, 0.f);
            h.w = fmaxf(acc.w * dn + bv.w, 0.f);
        }
        __half2 h01 = __float22half2_rn(make_float2(h.x, h.y));
        __half2 h23 = __float22half2_rn(make_float2(h.z, h.w));
        float2 packed;
        *(__half2*)&packed.x = h01;
        *(__half2*)&packed.y = h23;
        *(float2*)&xs[lr * 136 + f4 * 4] = packed;
    }
    __syncthreads();

    const int w = t >> 6;        // wave 0..7
    const int mrow = l & 15;
    const int kq = l >> 4;
    const int rgrp = (w & 3) * 16;   // row group
    const int cgrp = (w >> 2) * 4;   // col-tile group (4 tiles of 16)

    v8h a[4];
#pragma unroll
    for (int kk = 0; kk < 4; ++kk)
        a[kk] = *(const v8h*)&xs[(rgrp + mrow) * 136 + kk * 32 + kq * 8];

    v4f acc[4];
#pragma unroll
    for (int c = 0; c < 4; ++c) acc[c] = (v4f){0.f, 0.f, 0.f, 0.f};

#pragma unroll
    for (int kk = 0; kk < 4; ++kk) {
#pragma unroll
        for (int c = 0; c < 4; ++c) {
            v8h b = *(const v8h*)&Wt[(size_t)((cgrp + c) * 16 + mrow) * 128 + kk * 32 + kq * 8];
            acc[c] = __builtin_amdgcn_mfma_f32_16x16x32_f16(a[kk], b, acc[c], 0, 0, 0);
        }
    }

    float dn4[4];
#pragma unroll
    for (int r = 0; r < 4; ++r) {
        int grow = row0 + rgrp + kq * 4 + r;
        dn4[r] = (grow < nN) ? dis[grow] : 0.f;
    }
#pragma unroll
    for (int c = 0; c < 4; ++c) {
#pragma unroll
        for (int r = 0; r < 4; ++r) {
            int grow = row0 + rgrp + kq * 4 + r;
            if (grow < nN)
                HWS2[(size_t)grow * 128 + (cgrp + c) * 16 + mrow] =
                    __float2half(acc[c][r] * dn4[r]);
        }
    }
}

// FUSED layer-2 gather + layer-3 gemv:
//   hw3s[g] = dis[g] * dot(relu(dis[g]*Σ HWS2 + b2), W3)
__global__ __launch_bounds__(256) void k_gather_gemv(const __half* __restrict__ HWS2,
                                                     const int* __restrict__ row_ptr,
                                                     const int* __restrict__ src_csr,
                                                     const float* __restrict__ dis,
                                                     const float* __restrict__ bias,
                                                     const float* __restrict__ W3,
                                                     float* __restrict__ hw3s, int nN) {
    int g = blockIdx.x * 8 + (threadIdx.x >> 5);
    if (g >= nN) return;
    int f4 = threadIdx.x & 31;
    float4 acc = gather_row((const float2*)HWS2, row_ptr, src_csr, g, f4);
    float dn = dis[g];
    float4 bv = ((const float4*)bias)[f4];
    float4 w  = ((const float4*)W3)[f4];
    float sum = fmaxf(acc.x * dn + bv.x, 0.f) * w.x
              + fmaxf(acc.y * dn + bv.y, 0.f) * w.y
              + fmaxf(acc.z * dn + bv.z, 0.f) * w.z
              + fmaxf(acc.w * dn + bv.w, 0.f) * w.w;
#pragma unroll
    for (int off = 16; off > 0; off >>= 1) sum += __shfl_down(sum, off, 32);
    if (f4 == 0) hw3s[g] = sum * dn;
}

// scalar pull-aggregation + final relu -> d_out
__global__ __launch_bounds__(256) void k_gather3(const float* __restrict__ hw3s,
                                                 const int* __restrict__ row_ptr,
                                                 const int* __restrict__ src_csr,
                                                 const float* __restrict__ dis,
                                                 const float* __restrict__ b3,
                                                 float* __restrict__ out, int nN) {
    int i = blockIdx.x * 256 + threadIdx.x;
    if (i >= nN) return;
    float acc = hw3s[i];
    int beg = row_ptr[i], end = row_ptr[i + 1];
    for (int e = beg; e < end; ++e) acc += hw3s[src_csr[e]];
    out[i] = fmaxf(acc * dis[i] + b3[0], 0.f);
}

extern "C" void kernel_launch(void* const* d_in, const int* in_sizes, int n_in,
                              void* d_out, int out_size, void* d_ws, size_t ws_size,
                              hipStream_t stream) {
    const float* x  = (const float*)d_in[0];
    const int*   ei = (const int*)d_in[1];
    const float* W1 = (const float*)d_in[2];
    const float* b1 = (const float*)d_in[3];
    const float* W2 = (const float*)d_in[4];
    const float* b2 = (const float*)d_in[5];
    const float* W3 = (const float*)d_in[6];
    const float* b3 = (const float*)d_in[7];

    const int nN = in_sizes[0] / 128;
    const int nE = in_sizes[1] / 2;
    const int* src = ei;
    const int* dst = ei + nE;

    const int nB = (nN + 255) / 256;   // scan blocks (<=256)

    // workspace layout
    char* p = (char*)d_ws;
    int*    cnt      = (int*)p;           p += (size_t)nN * 4;
    int*    excl     = (int*)p;           p += (size_t)nN * 4;
    int*    blk_sum  = (int*)p;           p += (size_t)(nB + 1) * 4;
    int*    row_ptr  = (int*)p;           p += (size_t)(nN + 1) * 4;
    int*    rank     = (int*)p;           p += (size_t)nE * 4;
    int*    src_csr  = (int*)p;           p += (size_t)nE * 4;
    float*  dis      = (float*)p;         p += (size_t)nN * 4;
    float*  hw3s     = (float*)p;         p += (size_t)nN * 4;
    p = (char*)(((uintptr_t)p + 255) & ~(uintptr_t)255);
    __half* Wt1      = (__half*)p;        p += (size_t)128 * 128 * 2;
    __half* Wt2      = (__half*)p;        p += (size_t)128 * 128 * 2;
    __half* bufA     = (__half*)p;        p += (size_t)nN * 128 * 2;  // HWS1
    p = (char*)(((uintptr_t)p + 255) & ~(uintptr_t)255);
    __half* bufB     = (__half*)p;        p += (size_t)nN * 128 * 2;  // HWS2

    const int BE  = (nE + 255) / 256;
    const int BN  = (nN + 255) / 256;
    const int BG  = (nN + 63) / 64;
    const int BGA = (nN + 7) / 8;

    // --- CSR build + norms + weight cast ---
    hipMemsetAsync(cnt, 0, (size_t)nN * sizeof(int), stream);
    k_count_wcast<<<BE + 64, 256, 0, stream>>>(dst, cnt, rank, nE, BE,
                                               W1, W2, Wt1, Wt2);
    k_scan_blk<<<nB, 256, 0, stream>>>(cnt, dis, excl, blk_sum, nN);
    k_scan_add<<<nB, 256, 0, stream>>>(excl, blk_sum, row_ptr, nN, nB);

    // --- layer-1 GEMM (blocks [0,BG)) overlapped with atomic-free binning ---
    k_gemm_bin<<<BG + BE, 256, 0, stream>>>(x, Wt1, dis, bufA, nN, BG,
                                            src, dst, rank, row_ptr, src_csr, nE);

    // --- fused layer-1 gather + layer-2 GEMM: HWS1 -> HWS2 (512 thr) ---
    k_gather_gemm<<<BG, 512, 0, stream>>>(bufA, row_ptr, src_csr, dis, b1, Wt2,
                                          bufB, nN);

    // --- fused layer-2 gather + layer-3 gemv: HWS2 -> hw3s ---
    k_gather_gemv<<<BGA, 256, 0, stream>>>(bufB, row_ptr, src_csr, dis, b2, W3,
                                           hw3s, nN);

    // --- layer-3 scalar gather -> d_out ---
    k_gather3<<<BN, 256, 0, stream>>>(hw3s, row_ptr, src_csr, dis, b3,
                                      (float*)d_out, nN);
}

// Round 17
// 212.321 us; speedup vs baseline: 1.2330x; 1.0217x over previous
//
#include <hip/hip_runtime.h>
#include <hip/hip_fp16.h>

// ---------------------------------------------------------------------------
// 3-layer GCN, CSR-gather, fp16 dataflow + MFMA GEMM, fused pipeline:
//   count+wcast:  cnt histogram (stores per-edge rank!) || Wt cast
//   gemm1+bin:    HWS1 = half(dis*(x@W1))  ||  atomic-free CSR binning via rank
//   gather+gemm2: h1 = relu(dis*Σ HWS1 + b1) -> LDS -> HWS2 = half(dis*(h1@W2))
//                 [512 thr; QUARTER-WAVE gather: 16 lanes x 16B per node row
//                  -> one wave-load covers 4 rows (R17: request-rate fix)]
//   gather+gemv:  hw3s = dis * dot(relu(dis*Σ HWS2 + b2), W3)
//   gather3:      out = relu(dis*Σ hw3s + b3)
// Lessons: R4/R5 never force __launch_bounds__ min-waves. R7/R8/R16: gather is
// scattered-REQUEST-rate bound (bytes halved -> ~no change; balance -> no
// change). R13: keep hot kernels VGPR<64 (occupancy tier). R14/R15: rank trick.
// ---------------------------------------------------------------------------

typedef _Float16 v8h __attribute__((ext_vector_type(8)));
typedef float v4f __attribute__((ext_vector_type(4)));

// fused: edge count + rank record (blocks [0,BE)) + weight cast (blocks >=BE)
__global__ __launch_bounds__(256) void k_count_wcast(const int* __restrict__ dst,
                                                     int* __restrict__ cnt,
                                                     int* __restrict__ rank, int nE,
                                                     int BE,
                                                     const float* __restrict__ W1,
                                                     const float* __restrict__ W2,
                                                     __half* __restrict__ Wt1,
                                                     __half* __restrict__ Wt2) {
    int b = blockIdx.x;
    if (b < BE) {
        int e = b * 256 + threadIdx.x;
        if (e < nE) rank[e] = atomicAdd(&cnt[dst[e]], 1);
    } else {
        int i = (b - BE) * 256 + threadIdx.x;   // 0..16383
        int k = i >> 7, c = i & 127;
        Wt1[c * 128 + k] = __float2half(W1[i]);
        Wt2[c * 128 + k] = __float2half(W2[i]);
    }
}

// scan stage 1 + fused dis = rsqrt(cnt+1)
__global__ __launch_bounds__(256) void k_scan_blk(const int* __restrict__ cnt,
                                                  float* __restrict__ dis,
                                                  int* __restrict__ excl,
                                                  int* __restrict__ blk_sum, int nN) {
    __shared__ int sm[256];
    const int t = threadIdx.x;
    int i = blockIdx.x * 256 + t;
    int v = (i < nN) ? cnt[i] : 0;
    if (i < nN) dis[i] = rsqrtf((float)v + 1.0f);
    sm[t] = v;
    __syncthreads();
#pragma unroll
    for (int off = 1; off < 256; off <<= 1) {
        int x = (t >= off) ? sm[t - off] : 0;
        __syncthreads();
        sm[t] += x;
        __syncthreads();
    }
    if (i < nN) excl[i] = sm[t] - v;
    if (t == 255) blk_sum[blockIdx.x] = sm[255];
}

// stage 2+3 fused: every block scans blk_sum (nB<=256) in LDS, then adds.
__global__ __launch_bounds__(256) void k_scan_add(const int* __restrict__ excl,
                                                  const int* __restrict__ blk_sum,
                                                  int* __restrict__ row_ptr,
                                                  int nN, int nB) {
    __shared__ int sm[256];
    const int t = threadIdx.x;
    int v = (t < nB) ? blk_sum[t] : 0;
    sm[t] = v;
    __syncthreads();
#pragma unroll
    for (int off = 1; off < 256; off <<= 1) {
        int x = (t >= off) ? sm[t - off] : 0;
        __syncthreads();
        sm[t] += x;
        __syncthreads();
    }
    int i = blockIdx.x * 256 + t;
    if (i < nN) {
        int b = i >> 8;
        row_ptr[i] = excl[i] + sm[b] - blk_sum[b];
    }
    if (i == 0) row_ptr[nN] = sm[255];
}

// add 8 halves (packed in a float4) into acc[8] (fp32)
__device__ __forceinline__ void add8(float acc[8], float4 r) {
    __half2* hp = (__half2*)&r;
#pragma unroll
    for (int k = 0; k < 4; ++k) {
        float2 f = __half22float2(hp[k]);
        acc[2 * k] += f.x;
        acc[2 * k + 1] += f.y;
    }
}

// QUARTER-WAVE gather: 16 lanes per node row, 16B (8 halves) per lane.
// One wave-load instruction covers 4 node rows (1KB) -> half the scattered
// requests of the 32-lane/8B version. acc[8] fp32, includes self term.
__device__ __forceinline__ void gather_row16(const float4* __restrict__ Hv,
                                             const int* __restrict__ row_ptr,
                                             const int* __restrict__ src_csr,
                                             int g, int f8, float acc[8]) {
    int beg = row_ptr[g], end = row_ptr[g + 1];
#pragma unroll
    for (int k = 0; k < 8; ++k) acc[k] = 0.f;
    add8(acc, Hv[(size_t)g * 16 + f8]);   // self term
    int e = beg;
    for (; e + 4 <= end; e += 4) {        // 4-deep batch: r[4]x4 = 16 VGPRs
        int s[4];
#pragma unroll
        for (int j = 0; j < 4; ++j) s[j] = src_csr[e + j];
        float4 r[4];
#pragma unroll
        for (int j = 0; j < 4; ++j) r[j] = Hv[(size_t)s[j] * 16 + f8];
#pragma unroll
        for (int j = 0; j < 4; ++j) add8(acc, r[j]);
    }
    for (; e < end; ++e) add8(acc, Hv[(size_t)src_csr[e] * 16 + f8]);
}

// FUSED dispatch: blocks [0,BG) = layer-1 MFMA GEMM; blocks >=BG = CSR bin.
// Bin path is atomic-free: pos = row_ptr[dst] + rank (recorded during count).
__global__ __launch_bounds__(256) void k_gemm_bin(const float* __restrict__ X32,
                                                  const __half* __restrict__ Wt,
                                                  const float* __restrict__ dis,
                                                  __half* __restrict__ HWS,
                                                  int nrows, int BG,
                                                  const int* __restrict__ src,
                                                  const int* __restrict__ dst,
                                                  const int* __restrict__ rank,
                                                  const int* __restrict__ row_ptr,
                                                  int* __restrict__ src_csr, int nE) {
    __shared__ __half xs[64 * 136];
    if (blockIdx.x >= BG) {
        // --- binning path (no atomics) ---
        int e = (blockIdx.x - BG) * 256 + threadIdx.x;
        if (e < nE) {
            int d = dst[e];
            src_csr[row_ptr[d] + rank[e]] = src[e];
        }
        return;
    }

    // --- GEMM path ---
    const int t = threadIdx.x;
    const int row0 = blockIdx.x * 64;

#pragma unroll
    for (int i = 0; i < 8; ++i) {
        int f = t + i * 256;
        int r = f >> 5, k4 = f & 31;
        int gr = row0 + r;
        float4 v = make_float4(0.f, 0.f, 0.f, 0.f);
        if (gr < nrows) v = ((const float4*)X32)[(size_t)gr * 32 + k4];
        __half2 h01 = __float22half2_rn(make_float2(v.x, v.y));
        __half2 h23 = __float22half2_rn(make_float2(v.z, v.w));
        float2 packed;
        *(__half2*)&packed.x = h01;
        *(__half2*)&packed.y = h23;
        *(float2*)&xs[r * 136 + k4 * 4] = packed;
    }
    __syncthreads();

    const int w = t >> 6;
    const int l = t & 63;
    const int mrow = l & 15;
    const int kq = l >> 4;

    v8h a[4];
#pragma unroll
    for (int kk = 0; kk < 4; ++kk)
        a[kk] = *(const v8h*)&xs[(w * 16 + mrow) * 136 + kk * 32 + kq * 8];

    v4f acc[8];
#pragma unroll
    for (int c = 0; c < 8; ++c) acc[c] = (v4f){0.f, 0.f, 0.f, 0.f};

#pragma unroll
    for (int kk = 0; kk < 4; ++kk) {
#pragma unroll
        for (int c = 0; c < 8; ++c) {
            v8h b = *(const v8h*)&Wt[(size_t)(c * 16 + mrow) * 128 + kk * 32 + kq * 8];
            acc[c] = __builtin_amdgcn_mfma_f32_16x16x32_f16(a[kk], b, acc[c], 0, 0, 0);
        }
    }

    float dn[4];
#pragma unroll
    for (int r = 0; r < 4; ++r) {
        int grow = row0 + w * 16 + kq * 4 + r;
        dn[r] = (grow < nrows) ? dis[grow] : 0.f;
    }
#pragma unroll
    for (int c = 0; c < 8; ++c) {
#pragma unroll
        for (int r = 0; r < 4; ++r) {
            int grow = row0 + w * 16 + kq * 4 + r;
            if (grow < nrows)
                HWS[(size_t)grow * 128 + c * 16 + mrow] =
                    __float2half(acc[c][r] * dn[r]);
        }
    }
}

// FUSED layer-1 gather + layer-2 GEMM, 512 threads.
//   phase 1: 32 quarter-waves pull node slots from an LDS queue; each gathers
//            a full 128-col row with 16 lanes x 16B (4 rows per wave-load).
//   phase 2: 8 MFMA waves; wave w: rows (w&3)*16..+16, col-tiles (w>>2)*4..+4
__global__ __launch_bounds__(512) void k_gather_gemm(const __half* __restrict__ HWS1,
                                                     const int* __restrict__ row_ptr,
                                                     const int* __restrict__ src_csr,
                                                     const float* __restrict__ dis,
                                                     const float* __restrict__ bias,
                                                     const __half* __restrict__ Wt,
                                                     __half* __restrict__ HWS2,
                                                     int nN) {
    __shared__ __half xs[64 * 136];
    __shared__ int q;
    const int t = threadIdx.x;
    const int row0 = blockIdx.x * 64;
    const int l = t & 63;
    const int f8 = t & 15;            // lane within quarter-wave
    const int qbase = l & 48;         // base lane of this quarter in the wave
    const float4* Hv = (const float4*)HWS1;

    float bv[8];
    *(float4*)&bv[0] = ((const float4*)bias)[f8 * 2];
    *(float4*)&bv[4] = ((const float4*)bias)[f8 * 2 + 1];

    if (t == 0) q = 0;
    __syncthreads();

    for (;;) {
        int lr = 0;
        if (f8 == 0) lr = atomicAdd(&q, 1);
        lr = __shfl(lr, qbase, 64);
        if (lr >= 64) break;
        int g = row0 + lr;
        float acc[8];
        __half2 h[4];
        if (g < nN) {
            gather_row16(Hv, row_ptr, src_csr, g, f8, acc);
            float dn = dis[g];
#pragma unroll
            for (int k = 0; k < 4; ++k)
                h[k] = __float22half2_rn(make_float2(
                    fmaxf(acc[2 * k] * dn + bv[2 * k], 0.f),
                    fmaxf(acc[2 * k + 1] * dn + bv[2 * k + 1], 0.f)));
        } else {
#pragma unroll
            for (int k = 0; k < 4; ++k) h[k] = __float2half2_rn(0.f);
        }
        *(float4*)&xs[lr * 136 + f8 * 8] = *(float4*)h;   // 16B ds_write_b128
    }
    __syncthreads();

    const int w = t >> 6;        // wave 0..7
    const int mrow = l & 15;
    const int kq = l >> 4;
    const int rgrp = (w & 3) * 16;   // row group
    const int cgrp = (w >> 2) * 4;   // col-tile group (4 tiles of 16)

    v8h a[4];
#pragma unroll
    for (int kk = 0; kk < 4; ++kk)
        a[kk] = *(const v8h*)&xs[(rgrp + mrow) * 136 + kk * 32 + kq * 8];

    v4f acc[4];
#pragma unroll
    for (int c = 0; c < 4; ++c) acc[c] = (v4f){0.f, 0.f, 0.f, 0.f};

#pragma unroll
    for (int kk = 0; kk < 4; ++kk) {
#pragma unroll
        for (int c = 0; c < 4; ++c) {
            v8h b = *(const v8h*)&Wt[(size_t)((cgrp + c) * 16 + mrow) * 128 + kk * 32 + kq * 8];
            acc[c] = __builtin_amdgcn_mfma_f32_16x16x32_f16(a[kk], b, acc[c], 0, 0, 0);
        }
    }

    float dn4[4];
#pragma unroll
    for (int r = 0; r < 4; ++r) {
        int grow = row0 + rgrp + kq * 4 + r;
        dn4[r] = (grow < nN) ? dis[grow] : 0.f;
    }
#pragma unroll
    for (int c = 0; c < 4; ++c) {
#pragma unroll
        for (int r = 0; r < 4; ++r) {
            int grow = row0 + rgrp + kq * 4 + r;
            if (grow < nN)
                HWS2[(size_t)grow * 128 + (cgrp + c) * 16 + mrow] =
                    __float2half(acc[c][r] * dn4[r]);
        }
    }
}

// FUSED layer-2 gather + layer-3 gemv (quarter-wave gather, 16 nodes/block):
//   hw3s[g] = dis[g] * dot(relu(dis[g]*Σ HWS2 + b2), W3)
__global__ __launch_bounds__(256) void k_gather_gemv(const __half* __restrict__ HWS2,
                                                     const int* __restrict__ row_ptr,
                                                     const int* __restrict__ src_csr,
                                                     const float* __restrict__ dis,
                                                     const float* __restrict__ bias,
                                                     const float* __restrict__ W3,
                                                     float* __restrict__ hw3s, int nN) {
    int g = blockIdx.x * 16 + (threadIdx.x >> 4);
    if (g >= nN) return;
    int f8 = threadIdx.x & 15;
    float acc[8];
    gather_row16((const float4*)HWS2, row_ptr, src_csr, g, f8, acc);
    float dn = dis[g];
    float bv[8], w3[8];
    *(float4*)&bv[0] = ((const float4*)bias)[f8 * 2];
    *(float4*)&bv[4] = ((const float4*)bias)[f8 * 2 + 1];
    *(float4*)&w3[0] = ((const float4*)W3)[f8 * 2];
    *(float4*)&w3[4] = ((const float4*)W3)[f8 * 2 + 1];
    float sum = 0.f;
#pragma unroll
    for (int k = 0; k < 8; ++k)
        sum += fmaxf(acc[k] * dn + bv[k], 0.f) * w3[k];
#pragma unroll
    for (int off = 8; off > 0; off >>= 1) sum += __shfl_down(sum, off, 16);
    if (f8 == 0) hw3s[g] = sum * dn;
}

// scalar pull-aggregation + final relu -> d_out
__global__ __launch_bounds__(256) void k_gather3(const float* __restrict__ hw3s,
                                                 const int* __restrict__ row_ptr,
                                                 const int* __restrict__ src_csr,
                                                 const float* __restrict__ dis,
                                                 const float* __restrict__ b3,
                                                 float* __restrict__ out, int nN) {
    int i = blockIdx.x * 256 + threadIdx.x;
    if (i >= nN) return;
    float acc = hw3s[i];
    int beg = row_ptr[i], end = row_ptr[i + 1];
    for (int e = beg; e < end; ++e) acc += hw3s[src_csr[e]];
    out[i] = fmaxf(acc * dis[i] + b3[0], 0.f);
}

extern "C" void kernel_launch(void* const* d_in, const int* in_sizes, int n_in,
                              void* d_out, int out_size, void* d_ws, size_t ws_size,
                              hipStream_t stream) {
    const float* x  = (const float*)d_in[0];
    const int*   ei = (const int*)d_in[1];
    const float* W1 = (const float*)d_in[2];
    const float* b1 = (const float*)d_in[3];
    const float* W2 = (const float*)d_in[4];
    const float* b2 = (const float*)d_in[5];
    const float* W3 = (const float*)d_in[6];
    const float* b3 = (const float*)d_in[7];

    const int nN = in_sizes[0] / 128;
    const int nE = in_sizes[1] / 2;
    const int* src = ei;
    const int* dst = ei + nE;

    const int nB = (nN + 255) / 256;   // scan blocks (<=256)

    // workspace layout
    char* p = (char*)d_ws;
    int*    cnt      = (int*)p;           p += (size_t)nN * 4;
    int*    excl     = (int*)p;           p += (size_t)nN * 4;
    int*    blk_sum  = (int*)p;           p += (size_t)(nB + 1) * 4;
    int*    row_ptr  = (int*)p;           p += (size_t)(nN + 1) * 4;
    int*    rank     = (int*)p;           p += (size_t)nE * 4;
    int*    src_csr  = (int*)p;           p += (size_t)nE * 4;
    float*  dis      = (float*)p;         p += (size_t)nN * 4;
    float*  hw3s     = (float*)p;         p += (size_t)nN * 4;
    p = (char*)(((uintptr_t)p + 255) & ~(uintptr_t)255);
    __half* Wt1      = (__half*)p;        p += (size_t)128 * 128 * 2;
    __half* Wt2      = (__half*)p;        p += (size_t)128 * 128 * 2;
    __half* bufA     = (__half*)p;        p += (size_t)nN * 128 * 2;  // HWS1
    p = (char*)(((uintptr_t)p + 255) & ~(uintptr_t)255);
    __half* bufB     = (__half*)p;        p += (size_t)nN * 128 * 2;  // HWS2

    const int BE  = (nE + 255) / 256;
    const int BN  = (nN + 255) / 256;
    const int BG  = (nN + 63) / 64;
    const int BGV = (nN + 15) / 16;

    // --- CSR build + norms + weight cast ---
    hipMemsetAsync(cnt, 0, (size_t)nN * sizeof(int), stream);
    k_count_wcast<<<BE + 64, 256, 0, stream>>>(dst, cnt, rank, nE, BE,
                                               W1, W2, Wt1, Wt2);
    k_scan_blk<<<nB, 256, 0, stream>>>(cnt, dis, excl, blk_sum, nN);
    k_scan_add<<<nB, 256, 0, stream>>>(excl, blk_sum, row_ptr, nN, nB);

    // --- layer-1 GEMM (blocks [0,BG)) overlapped with atomic-free binning ---
    k_gemm_bin<<<BG + BE, 256, 0, stream>>>(x, Wt1, dis, bufA, nN, BG,
                                            src, dst, rank, row_ptr, src_csr, nE);

    // --- fused layer-1 gather + layer-2 GEMM: HWS1 -> HWS2 (512 thr) ---
    k_gather_gemm<<<BG, 512, 0, stream>>>(bufA, row_ptr, src_csr, dis, b1, Wt2,
                                          bufB, nN);

    // --- fused layer-2 gather + layer-3 gemv: HWS2 -> hw3s ---
    k_gather_gemv<<<BGV, 256, 0, stream>>>(bufB, row_ptr, src_csr, dis, b2, W3,
                                           hw3s, nN);

    // --- layer-3 scalar gather -> d_out ---
    k_gather3<<<BN, 256, 0, stream>>>(hw3s, row_ptr, src_csr, dis, b3,
                                      (float*)d_out, nN);
}